// Round 5
// baseline (57.405 us; speedup 1.0000x reference)
//
#include <hip/hip_runtime.h>
#include <math.h>

#define NPTS 1024
#define WPB 4                 // waves (= batches) per block
#define THREADS (64 * WPB)

template <int CTRL>
__device__ __forceinline__ float dpp_add(float v) {
  int m = __builtin_amdgcn_update_dpp(0, __builtin_bit_cast(int, v), CTRL, 0xF, 0xF, true);
  return v + __builtin_bit_cast(float, m);
}

// full 64-lane sum, total in lane 63; pure VALU
__device__ __forceinline__ float wave_red_full(float v) {
  v = dpp_add<0x111>(v);  // row_shr:1
  v = dpp_add<0x112>(v);  // row_shr:2
  v = dpp_add<0x114>(v);  // row_shr:4
  v = dpp_add<0x118>(v);  // row_shr:8
  v = dpp_add<0x142>(v);  // row_bcast:15
  v = dpp_add<0x143>(v);  // row_bcast:31
  return v;
}

// broadcast lane-63 total to an SGPR-resident uniform float
__device__ __forceinline__ float red_total(float v) {
  return __builtin_bit_cast(float,
      __builtin_amdgcn_readlane(__builtin_bit_cast(int, wave_red_full(v)), 63));
}

__device__ __forceinline__ double rl_f64(double v, int l) {
  typedef int v2i __attribute__((ext_vector_type(2)));
  v2i u = __builtin_bit_cast(v2i, v);
  v2i r;
  r.x = __builtin_amdgcn_readlane(u.x, l);
  r.y = __builtin_amdgcn_readlane(u.y, l);
  return __builtin_bit_cast(double, r);
}

__device__ __forceinline__ float bperm_f(int srclane, float v) {
  return __builtin_bit_cast(float,
      __builtin_amdgcn_ds_bpermute(srclane << 2, __builtin_bit_cast(int, v)));
}

__global__ void __launch_bounds__(THREADS) deepfit_kernel(
    const float* __restrict__ pts, const float* __restrict__ wts,
    float* __restrict__ beta_out, float* __restrict__ nest_out,
    float* __restrict__ nn_out, int B)
{
  const int lane = threadIdx.x & 63;
  const int wid = threadIdx.x >> 6;
  const int b = blockIdx.x * WPB + wid;
  if (b >= B) return;

  __shared__ double s_L[WPB][100];
  double* sL = &s_L[wid][0];

  const float4* px4 = reinterpret_cast<const float4*>(pts + (size_t)b * (3 * NPTS));
  const float4* pw4 = reinterpret_cast<const float4*>(wts + (size_t)b * NPTS);

  // ---- moments: 28 of w*x^a*y^b (a+b<=6) + 10 of w*z*x^a*y^b (a+b<=3), RAW
  //      coords (h cancels exactly in beta). Optimistic w; w=1 redo is rare. ----
  float M[28], Z[10];
  float habs = 0.f;
  int cnt = 0;

  for (int pass = 0; pass < 2; ++pass) {
#pragma unroll
    for (int i = 0; i < 28; ++i) M[i] = 0.f;
#pragma unroll
    for (int i = 0; i < 10; ++i) Z[i] = 0.f;

#pragma unroll
    for (int c = 0; c < 4; ++c) {
      float4 x4 = px4[lane + 64 * c];
      float4 y4 = px4[256 + lane + 64 * c];
      float4 z4 = px4[512 + lane + 64 * c];
      float4 w4 = pw4[lane + 64 * c];
      float xs[4] = {x4.x, x4.y, x4.z, x4.w};
      float ys[4] = {y4.x, y4.y, y4.z, y4.w};
      float zs[4] = {z4.x, z4.y, z4.z, z4.w};
      float ws[4] = {w4.x, w4.y, w4.z, w4.w};
      if (pass == 0) {
#pragma unroll
        for (int p = 0; p < 4; ++p) {
          habs += fabsf(xs[p]) + fabsf(ys[p]);
          cnt += (int)__popcll(__ballot(ws[p] > 0.001f));  // wave-total per ballot
        }
      }
#pragma unroll
      for (int p = 0; p < 4; ++p) {
        float x = xs[p], y = ys[p];
        float w = (pass == 0) ? ws[p] : 1.0f;
        float wz = w * zs[p];
        float yp1 = y, yp2 = y * y, yp3 = yp2 * y, yp4 = yp3 * y, yp5 = yp4 * y, yp6 = yp5 * y;
        float tx = w;
        M[0] += tx; M[1] += tx * yp1; M[2] += tx * yp2; M[3] += tx * yp3; M[4] += tx * yp4; M[5] += tx * yp5; M[6] += tx * yp6;
        tx *= x;
        M[7] += tx; M[8] += tx * yp1; M[9] += tx * yp2; M[10] += tx * yp3; M[11] += tx * yp4; M[12] += tx * yp5;
        tx *= x;
        M[13] += tx; M[14] += tx * yp1; M[15] += tx * yp2; M[16] += tx * yp3; M[17] += tx * yp4;
        tx *= x;
        M[18] += tx; M[19] += tx * yp1; M[20] += tx * yp2; M[21] += tx * yp3;
        tx *= x;
        M[22] += tx; M[23] += tx * yp1; M[24] += tx * yp2;
        tx *= x;
        M[25] += tx; M[26] += tx * yp1;
        tx *= x;
        M[27] += tx;
        float tz = wz;
        Z[0] += tz; Z[1] += tz * yp1; Z[2] += tz * yp2; Z[3] += tz * yp3;
        tz *= x;
        Z[4] += tz; Z[5] += tz * yp1; Z[6] += tz * yp2;
        tz *= x;
        Z[7] += tz; Z[8] += tz * yp1;
        tz *= x;
        Z[9] += tz;
      }
    }
    if (pass == 1) break;
    if (cnt > 18) break;  // wave-uniform; redo with w=1 essentially never
  }

  // ---- intra-wave reduce: 39 totals; deposit moment k into lane k of momvec ----
  float momvec = 0.f;
#pragma unroll
  for (int i = 0; i < 28; ++i) {
    float tot = red_total(M[i]);          // uniform (SGPR)
    momvec = (lane == i) ? tot : momvec;  // v_cmp + v_cndmask
  }
#pragma unroll
  for (int i = 0; i < 10; ++i) {
    float tot = red_total(Z[i]);
    momvec = (lane == 28 + i) ? tot : momvec;
  }
  float mh;
  {
    float htot = red_total(habs);
    mh = htot * (1.0f / 2048.0f);  // (mean|x| + mean|y|)/2
    if (fabsf(mh) < 1e-4f) mh = 0.1f;
  }

  // ---- gather row `lane` of raw XtX + rhs via ds_bpermute (all lanes) ----
  const int lc = (lane < 10) ? lane : 0;
  const int axi = (0x18D21u >> (2 * lc)) & 3;  // x-exp of {x,y,x2,y2,xy,x3,y3,x2y,xy2,1}
  const int ayi = (0x27184u >> (2 * lc)) & 3;  // y-exp
  constexpr int AXC[10] = {1, 0, 2, 0, 1, 3, 0, 2, 1, 0};
  constexpr int AYC[10] = {0, 1, 0, 2, 1, 0, 3, 1, 2, 0};
  double a[10], yy;
#pragma unroll
  for (int j = 0; j < 10; ++j) {
    int as = axi + AXC[j];
    int bs = ayi + AYC[j];
    int idx = as * 7 - (as * (as - 1)) / 2 + bs;  // moment index, a+b<=6
    a[j] = (double)bperm_f(idx, momvec);
  }
  {
    int zi = axi * 4 - (axi * (axi - 1)) / 2 + ayi;  // z-moment index, a+b<=3
    yy = (double)bperm_f(28 + zi, momvec);
  }

  // ---- lanes 0..9: f64 LDL^T + solves, all same-wave (no barriers) ----
  float bf = 0.f;
  if (lane < 10) {
    double Lc[10];
    double rd_own = 1.0;
#pragma unroll
    for (int j = 0; j < 10; ++j) {
      double dj = rl_f64(a[j], j);
      double rdj = 1.0 / dj;
      double lij = a[j] * rdj;  // L[i][j] for i>j
      Lc[j] = lij;
      if (lane == j) rd_own = rdj;
      double wj = rl_f64(yy, j);
      if (lane > j) yy -= lij * wj;  // forward solve L w = y
#pragma unroll
      for (int k = j + 1; k < 10; ++k) {
        double ajk = rl_f64(a[k], j);  // A[j][k] at lane j
        a[k] -= lij * ajk;             // trailing update
      }
    }
    yy *= rd_own;  // apply D^{-1}
#pragma unroll
    for (int j = 0; j < 10; ++j) sL[lane * 10 + j] = Lc[j];
    asm volatile("s_waitcnt lgkmcnt(0)" ::: "memory");  // same-wave DS in-order
    __builtin_amdgcn_sched_barrier(0);
#pragma unroll
    for (int j = 9; j >= 0; --j) {  // back solve L^T beta = v (unit diag)
      double xj = rl_f64(yy, j);
      if (lane < j) yy -= sL[j * 10 + lane] * xj;
    }
    bf = (float)yy;  // raw solve IS final beta (h cancels)
    beta_out[(size_t)b * 10 + lane] = bf;
    double b0 = rl_f64(yy, 0);
    double b1 = rl_f64(yy, 1);
    if (lane == 0) {
      double invn = 1.0 / sqrt(b0 * b0 + b1 * b1 + 1.0);
      nest_out[(size_t)b * 3 + 0] = (float)(-b0 * invn);
      nest_out[(size_t)b * 3 + 1] = (float)(-b1 * invn);
      nest_out[(size_t)b * 3 + 2] = (float)invn;
    }
  }

  // ---- broadcast beta via readlane (uniform) ----
  float bb[10];
#pragma unroll
  for (int j = 0; j < 10; ++j)
    bb[j] = __builtin_bit_cast(float, __builtin_amdgcn_readlane(__builtin_bit_cast(int, bf), j));

  // ---- normals: reload x,y (L2-hit), scaled by 1/h ----
  const float inv_h = 1.0f / mh;
  float4* o4 = reinterpret_cast<float4*>(nn_out + (size_t)b * (NPTS * 3));
#pragma unroll
  for (int c = 0; c < 4; ++c) {
    float4 x4 = px4[lane + 64 * c];
    float4 y4 = px4[256 + lane + 64 * c];
    float xs[4] = {x4.x, x4.y, x4.z, x4.w};
    float ys[4] = {y4.x, y4.y, y4.z, y4.w};
    float nx[4], ny[4], nz[4];
#pragma unroll
    for (int p = 0; p < 4; ++p) {
      float x = xs[p] * inv_h;
      float y = ys[p] * inv_h;
      float x2 = x * x, y2 = y * y, xy = x * y;
      float vx = -(bb[0] + 2.f * bb[2] * x + bb[4] * y + 3.f * bb[5] * x2 + 2.f * bb[7] * xy + bb[8] * y2);
      float vy = -(bb[1] + 2.f * bb[3] * y + bb[4] * x + 3.f * bb[6] * y2 + bb[7] * x2 + 2.f * bb[8] * xy);
      float invn = 1.0f / sqrtf(vx * vx + vy * vy + 1.0f);
      nx[p] = vx * invn; ny[p] = vy * invn; nz[p] = invn;
    }
    float4 f0 = make_float4(nx[0], ny[0], nz[0], nx[1]);
    float4 f1 = make_float4(ny[1], nz[1], nx[2], ny[2]);
    float4 f2 = make_float4(nz[2], nx[3], ny[3], nz[3]);
    o4[192 * c + 3 * lane + 0] = f0;
    o4[192 * c + 3 * lane + 1] = f1;
    o4[192 * c + 3 * lane + 2] = f2;
  }
}

extern "C" void kernel_launch(void* const* d_in, const int* in_sizes, int n_in,
                              void* d_out, int out_size, void* d_ws, size_t ws_size,
                              hipStream_t stream) {
  const float* pts = (const float*)d_in[0];
  const float* wts = (const float*)d_in[1];
  float* out = (float*)d_out;
  const int B = in_sizes[1] / NPTS;
  float* beta_out = out;
  float* nest_out = out + (size_t)B * 10;
  float* nn_out = out + (size_t)B * 13;
  const int grid = (B + WPB - 1) / WPB;
  deepfit_kernel<<<grid, THREADS, 0, stream>>>(pts, wts, beta_out, nest_out, nn_out, B);
}